// Round 3
// baseline (510.083 us; speedup 1.0000x reference)
//
#include <hip/hip_runtime.h>
#include <hip/hip_cooperative_groups.h>

namespace cg = cooperative_groups;

#define BB 32
#define NN 2048
#define HH 512

static __device__ __forceinline__ float dot4(float4 a, float4 b) {
    return a.x * b.x + a.y * b.y + a.z * b.z + a.w * b.w;
}

static __device__ __forceinline__ float waveRedSum(float s) {
#pragma unroll
    for (int off = 32; off > 0; off >>= 1) s += __shfl_down(s, off, 64);
    return s;
}

// Single cooperative kernel: 512 blocks x 256 threads (2 blocks/CU co-resident).
// Phases: A scores -> B softmax -> C weighted V-sum -> D output GEMV,
// separated by grid.sync(). Softmax is shift-invariant so Q·wq + b_att is
// dropped from the score (cancels exactly).
__global__ void __launch_bounds__(256, 2)
k_fused(const float* __restrict__ Q, const float* __restrict__ K,
        const float* __restrict__ V, const int* __restrict__ adj,
        const int* __restrict__ s_mask, const float* __restrict__ w_att,
        const float* __restrict__ Wr0, const float* __restrict__ Wr1,
        const float* __restrict__ Wri, float* __restrict__ out,
        float* __restrict__ ws) {
    cg::grid_group grid = cg::this_grid();
    float* attn = out;                 // B*N floats (output 0)
    float* attn_sum = out + BB * NN;   // B*H floats (output 1)
    float* u0 = ws;                    // B*H
    float* u1 = ws + BB * HH;          // B*H

    __shared__ float smem[1280];       // reused across phases (grid.sync between)

    int t = threadIdx.x;
    int blk = blockIdx.x;              // 512
    int gtid = blk * 256 + t;          // 131072
    int wave = gtid >> 6;              // 2048 waves
    int lane = t & 63;

    // zero u0/u1 (ws is poisoned 0xAA by harness) — visible after grid.sync
    if (gtid < 2 * BB * HH) ws[gtid] = 0.0f;

    // ---- Phase A: scores[b,n] = adj ? K[b,n]·wk : -1e30 ----
    // B*N = 65536 rows over 2048 waves -> 32 rows per wave.
    {
        const float* wk = w_att + HH;
        float4 a0 = *(const float4*)(wk + lane * 4);
        float4 a1 = *(const float4*)(wk + 256 + lane * 4);
#pragma unroll 4
        for (int i = 0; i < 32; i++) {
            int r = wave * 32 + i;
            size_t base = (size_t)r * HH;
            float4 k0 = *(const float4*)(K + base + lane * 4);
            float4 k1 = *(const float4*)(K + base + 256 + lane * 4);
            float s = waveRedSum(dot4(k0, a0) + dot4(k1, a1));
            if (lane == 0) attn[r] = adj[r] ? s : -1e30f;
        }
    }
    grid.sync();

    // ---- Phase B: in-place softmax over n, blocks 0..31 (tiny) ----
    if (blk < BB) {
        float* red = smem;
        int b = blk;
        float v[8];
        float m = -INFINITY;
#pragma unroll
        for (int i = 0; i < 8; i++) {
            v[i] = attn[b * NN + t * 8 + i];
            m = fmaxf(m, v[i]);
        }
#pragma unroll
        for (int off = 32; off > 0; off >>= 1) m = fmaxf(m, __shfl_xor(m, off, 64));
        if (lane == 0) red[t >> 6] = m;
        __syncthreads();
        float m4 = fmaxf(fmaxf(red[0], red[1]), fmaxf(red[2], red[3]));
        float sum = 0.0f;
#pragma unroll
        for (int i = 0; i < 8; i++) {
            v[i] = expf(v[i] - m4);
            sum += v[i];
        }
#pragma unroll
        for (int off = 32; off > 0; off >>= 1) sum += __shfl_xor(sum, off, 64);
        __syncthreads();
        if (lane == 0) red[t >> 6] = sum;
        __syncthreads();
        float inv = 1.0f / (red[0] + red[1] + red[2] + red[3]);
#pragma unroll
        for (int i = 0; i < 8; i++) attn[b * NN + t * 8 + i] = v[i] * inv;
    }
    grid.sync();

    // ---- Phase C: u0/u1[b,h] += sum_n attn*(sm / 1-sm)*V[b,n,h] ----
    {
        float* w0s = smem;           // [128]
        float* w1s = smem + 128;     // [128]
        float* comb = smem + 256;    // [1024]
        int b = blk >> 4;
        int n0 = (blk & 15) * 128;   // 128-row chunk
        int h4 = (t & 127) * 4;
        int half = t >> 7;           // rows [0,64) or [64,128) of the chunk
        if (t < 128) {
            float w = attn[b * NN + n0 + t];
            int sm = s_mask[b * NN + n0 + t];
            w0s[t] = sm ? w : 0.0f;
            w1s[t] = sm ? 0.0f : w;
        }
        __syncthreads();
        float4 a0 = {0, 0, 0, 0}, a1 = {0, 0, 0, 0};
        const float* Vb = V + ((size_t)(b * NN + n0 + half * 64)) * HH + h4;
#pragma unroll 4
        for (int i = 0; i < 64; i++) {
            float4 x = *(const float4*)(Vb + (size_t)i * HH);
            float w0 = w0s[half * 64 + i];
            float w1 = w1s[half * 64 + i];
            a0.x += w0 * x.x; a0.y += w0 * x.y; a0.z += w0 * x.z; a0.w += w0 * x.w;
            a1.x += w1 * x.x; a1.y += w1 * x.y; a1.z += w1 * x.z; a1.w += w1 * x.w;
        }
        // combine the two halves through LDS -> halves the global atomics
        if (half == 1) {
            int i8 = (t - 128) * 8;
            comb[i8 + 0] = a0.x; comb[i8 + 1] = a0.y; comb[i8 + 2] = a0.z; comb[i8 + 3] = a0.w;
            comb[i8 + 4] = a1.x; comb[i8 + 5] = a1.y; comb[i8 + 6] = a1.z; comb[i8 + 7] = a1.w;
        }
        __syncthreads();
        if (half == 0) {
            int i8 = t * 8;
            a0.x += comb[i8 + 0]; a0.y += comb[i8 + 1]; a0.z += comb[i8 + 2]; a0.w += comb[i8 + 3];
            a1.x += comb[i8 + 4]; a1.y += comb[i8 + 5]; a1.z += comb[i8 + 6]; a1.w += comb[i8 + 7];
            float* p0 = u0 + b * HH + h4;
            float* p1 = u1 + b * HH + h4;
            atomicAdd(p0 + 0, a0.x); atomicAdd(p0 + 1, a0.y);
            atomicAdd(p0 + 2, a0.z); atomicAdd(p0 + 3, a0.w);
            atomicAdd(p1 + 0, a1.x); atomicAdd(p1 + 1, a1.y);
            atomicAdd(p1 + 2, a1.z); atomicAdd(p1 + 3, a1.w);
        }
    }
    grid.sync();

    // ---- Phase D: attn_sum[b,o] = Wr0[o]·u0[b] + Wr1[o]·u1[b] + Wri[o]·Q[b] ----
    // B*H = 16384 outputs over 2048 waves -> 8 per wave.
    {
#pragma unroll
        for (int i = 0; i < 8; i++) {
            int unit = wave * 8 + i;
            int b = unit >> 9;
            int o = unit & 511;
            const float* q = Q + b * HH;
            const float* x0 = u0 + b * HH;
            const float* x1 = u1 + b * HH;
            const float* r0 = Wr0 + (size_t)o * HH;
            const float* r1 = Wr1 + (size_t)o * HH;
            const float* ri = Wri + (size_t)o * HH;
            float s = 0.0f;
#pragma unroll
            for (int part = 0; part < 2; part++) {
                int h = part * 256 + lane * 4;
                s += dot4(*(const float4*)(r0 + h), *(const float4*)(x0 + h));
                s += dot4(*(const float4*)(r1 + h), *(const float4*)(x1 + h));
                s += dot4(*(const float4*)(ri + h), *(const float4*)(q + h));
            }
            s = waveRedSum(s);
            if (lane == 0) attn_sum[unit] = s;
        }
    }
}

extern "C" void kernel_launch(void* const* d_in, const int* in_sizes, int n_in,
                              void* d_out, int out_size, void* d_ws, size_t ws_size,
                              hipStream_t stream) {
    const float* Q = (const float*)d_in[0];
    const float* K = (const float*)d_in[1];
    const float* V = (const float*)d_in[2];
    const int* adj = (const int*)d_in[3];
    const int* s_mask = (const int*)d_in[4];
    const float* w_att = (const float*)d_in[5];
    // d_in[6] = b_att: unused — softmax invariant to per-row constants.
    const float* Wr0 = (const float*)d_in[7];
    const float* Wr1 = (const float*)d_in[8];
    const float* Wri = (const float*)d_in[9];
    float* out = (float*)d_out;
    float* ws = (float*)d_ws;

    void* args[] = {&Q, &K, &V, &adj, &s_mask, &w_att, &Wr0, &Wr1, &Wri, &out, &ws};
    hipLaunchCooperativeKernel((void*)k_fused, dim3(512), dim3(256), args, 0, stream);
}

// Round 4
// 304.094 us; speedup vs baseline: 1.6774x; 1.6774x over previous
//
#include <hip/hip_runtime.h>

#define BB 32
#define NN 2048
#define HH 512

static __device__ __forceinline__ float dot4(float4 a, float4 b) {
    return a.x * b.x + a.y * b.y + a.z * b.z + a.w * b.w;
}

// ws layout (floats): u0[0,16384) u1[16384,32768) m[32768,32800) inv[32800,32832)

// Kernel 1: scores[b,n] = adj ? K[b,n]·wk : -1e30 (raw, into attn region).
// Softmax is shift-invariant so Q·wq + b_att cancels exactly — dropped.
// Also zeroes u0/u1 (harness poisons ws with 0xAA).
__global__ void k_scores(const float* __restrict__ K,
                         const float* __restrict__ w_att,
                         const int* __restrict__ adj,
                         float* __restrict__ scores,
                         float* __restrict__ ws) {
    int gtid = blockIdx.x * blockDim.x + threadIdx.x;
    if (gtid < 2 * BB * HH) ws[gtid] = 0.0f;  // zero u0/u1 for k_wsum atomics
    int wave = gtid >> 6;
    int lane = threadIdx.x & 63;
    if (wave >= BB * NN) return;
    const float* wk = w_att + HH;
    size_t base = (size_t)wave * HH;
    float4 k0 = *(const float4*)(K + base + lane * 4);
    float4 k1 = *(const float4*)(K + base + 256 + lane * 4);
    float4 a0 = *(const float4*)(wk + lane * 4);
    float4 a1 = *(const float4*)(wk + 256 + lane * 4);
    float s = dot4(k0, a0) + dot4(k1, a1);
#pragma unroll
    for (int off = 32; off > 0; off >>= 1) s += __shfl_down(s, off, 64);
    if (lane == 0) scores[wave] = adj[wave] ? s : -1e30f;
}

// Kernel 2: per-batch softmax stats. stats[b] = rowmax, stats[32+b] = 1/sum(exp).
__global__ void k_rowstats(const float* __restrict__ scores,
                           float* __restrict__ stats) {
    __shared__ float red[4];
    int b = blockIdx.x;
    int t = threadIdx.x;
    float v[8];
    float m = -INFINITY;
#pragma unroll
    for (int i = 0; i < 8; i++) {
        v[i] = scores[b * NN + t * 8 + i];
        m = fmaxf(m, v[i]);
    }
#pragma unroll
    for (int off = 32; off > 0; off >>= 1) m = fmaxf(m, __shfl_xor(m, off, 64));
    if ((t & 63) == 0) red[t >> 6] = m;
    __syncthreads();
    float m4 = fmaxf(fmaxf(red[0], red[1]), fmaxf(red[2], red[3]));
    float sum = 0.0f;
#pragma unroll
    for (int i = 0; i < 8; i++) sum += expf(v[i] - m4);
#pragma unroll
    for (int off = 32; off > 0; off >>= 1) sum += __shfl_xor(sum, off, 64);
    __syncthreads();
    if ((t & 63) == 0) red[t >> 6] = sum;
    __syncthreads();
    if (t == 0) {
        stats[b] = m4;
        stats[32 + b] = 1.0f / (red[0] + red[1] + red[2] + red[3]);
    }
}

// Kernel 3: normalize attn in-place AND accumulate
//   u0[b,h] += sum_n attn*sm*V[b,n,h] ; u1[b,h] += sum_n attn*(1-sm)*V[b,n,h]
// grid = B*16 blocks (128-row chunks) x 256 threads; thread covers 4 h, 64 rows.
__global__ void k_wsum(const float* __restrict__ V,
                       float* __restrict__ attn,
                       const int* __restrict__ s_mask,
                       const float* __restrict__ stats,
                       float* __restrict__ u0,
                       float* __restrict__ u1) {
    int b = blockIdx.x >> 4;
    int n0 = (blockIdx.x & 15) * 128;
    int t = threadIdx.x;
    int h4 = (t & 127) * 4;
    int half = t >> 7;  // rows [0,64) or [64,128) of the chunk
    __shared__ float w0s[128], w1s[128], comb[1024];
    if (t < 128) {
        float mb = stats[b];
        float invb = stats[32 + b];
        float w = expf(attn[b * NN + n0 + t] - mb) * invb;
        attn[b * NN + n0 + t] = w;  // output 0, normalized
        int sm = s_mask[b * NN + n0 + t];
        w0s[t] = sm ? w : 0.0f;
        w1s[t] = sm ? 0.0f : w;
    }
    __syncthreads();
    float4 a0 = {0, 0, 0, 0}, a1 = {0, 0, 0, 0};
    const float* Vb = V + ((size_t)(b * NN + n0 + half * 64)) * HH + h4;
#pragma unroll 4
    for (int i = 0; i < 64; i++) {
        float4 x = *(const float4*)(Vb + (size_t)i * HH);
        float w0 = w0s[half * 64 + i];
        float w1 = w1s[half * 64 + i];
        a0.x += w0 * x.x; a0.y += w0 * x.y; a0.z += w0 * x.z; a0.w += w0 * x.w;
        a1.x += w1 * x.x; a1.y += w1 * x.y; a1.z += w1 * x.z; a1.w += w1 * x.w;
    }
    // combine the two halves through LDS -> halves the global atomics
    if (half == 1) {
        int i8 = (t - 128) * 8;
        comb[i8 + 0] = a0.x; comb[i8 + 1] = a0.y; comb[i8 + 2] = a0.z; comb[i8 + 3] = a0.w;
        comb[i8 + 4] = a1.x; comb[i8 + 5] = a1.y; comb[i8 + 6] = a1.z; comb[i8 + 7] = a1.w;
    }
    __syncthreads();
    if (half == 0) {
        int i8 = t * 8;
        a0.x += comb[i8 + 0]; a0.y += comb[i8 + 1]; a0.z += comb[i8 + 2]; a0.w += comb[i8 + 3];
        a1.x += comb[i8 + 4]; a1.y += comb[i8 + 5]; a1.z += comb[i8 + 6]; a1.w += comb[i8 + 7];
        float* p0 = u0 + b * HH + h4;
        float* p1 = u1 + b * HH + h4;
        atomicAdd(p0 + 0, a0.x); atomicAdd(p0 + 1, a0.y);
        atomicAdd(p0 + 2, a0.z); atomicAdd(p0 + 3, a0.w);
        atomicAdd(p1 + 0, a1.x); atomicAdd(p1 + 1, a1.y);
        atomicAdd(p1 + 2, a1.z); atomicAdd(p1 + 3, a1.w);
    }
}

// Kernel 4: attn_sum[b,o] = Wr0[o]·u0[b] + Wr1[o]·u1[b] + Wri[o]·Q[b], one wave per (b,o)
__global__ void k_out(const float* __restrict__ Q,
                      const float* __restrict__ Wr0,
                      const float* __restrict__ Wr1,
                      const float* __restrict__ Wri,
                      const float* __restrict__ u0,
                      const float* __restrict__ u1,
                      float* __restrict__ out) {
    int wave = (blockIdx.x * blockDim.x + threadIdx.x) >> 6;
    int lane = threadIdx.x & 63;
    if (wave >= BB * HH) return;
    int b = wave >> 9;
    int o = wave & 511;
    const float* q = Q + b * HH;
    const float* x0 = u0 + b * HH;
    const float* x1 = u1 + b * HH;
    const float* r0 = Wr0 + (size_t)o * HH;
    const float* r1 = Wr1 + (size_t)o * HH;
    const float* ri = Wri + (size_t)o * HH;
    float s = 0.0f;
#pragma unroll
    for (int part = 0; part < 2; part++) {
        int h = part * 256 + lane * 4;
        s += dot4(*(const float4*)(r0 + h), *(const float4*)(x0 + h));
        s += dot4(*(const float4*)(r1 + h), *(const float4*)(x1 + h));
        s += dot4(*(const float4*)(ri + h), *(const float4*)(q + h));
    }
#pragma unroll
    for (int off = 32; off > 0; off >>= 1) s += __shfl_down(s, off, 64);
    if (lane == 0) out[wave] = s;
}

extern "C" void kernel_launch(void* const* d_in, const int* in_sizes, int n_in,
                              void* d_out, int out_size, void* d_ws, size_t ws_size,
                              hipStream_t stream) {
    const float* Q = (const float*)d_in[0];
    const float* K = (const float*)d_in[1];
    const float* V = (const float*)d_in[2];
    const int* adj = (const int*)d_in[3];
    const int* s_mask = (const int*)d_in[4];
    const float* w_att = (const float*)d_in[5];
    // d_in[6] = b_att: unused — softmax invariant to per-row constants.
    const float* Wr0 = (const float*)d_in[7];
    const float* Wr1 = (const float*)d_in[8];
    const float* Wri = (const float*)d_in[9];

    float* out = (float*)d_out;
    float* attn = out;                // B*N floats (output 0)
    float* attn_sum = out + BB * NN;  // B*H floats (output 1)
    float* ws = (float*)d_ws;
    float* u0 = ws;
    float* u1 = ws + BB * HH;
    float* stats = ws + 2 * BB * HH;  // m[32] then inv[32]

    k_scores<<<(BB * NN) / 4, 256, 0, stream>>>(K, w_att, adj, attn, ws);
    k_rowstats<<<BB, 256, 0, stream>>>(attn, stats);
    k_wsum<<<BB * 16, 256, 0, stream>>>(V, attn, s_mask, stats, u0, u1);
    k_out<<<(BB * HH) / 4, 256, 0, stream>>>(Q, Wr0, Wr1, Wri, u0, u1, attn_sum);
}

// Round 5
// 301.350 us; speedup vs baseline: 1.6927x; 1.0091x over previous
//
#include <hip/hip_runtime.h>

#define BB 32
#define NN 2048
#define HH 512

static __device__ __forceinline__ float dot4(float4 a, float4 b) {
    return a.x * b.x + a.y * b.y + a.z * b.z + a.w * b.w;
}

// ws layout (floats): u0[0,16384) u1[16384,32768) scores[32768,98304)

// Kernel 1: scores[b,n] = adj ? K[b,n]·wk : -1e30 (raw, into ws scratch).
// Softmax is shift-invariant so Q·wq + b_att cancels exactly — dropped.
// Also zeroes u0/u1 (harness poisons ws with 0xAA).
__global__ void k_scores(const float* __restrict__ K,
                         const float* __restrict__ w_att,
                         const int* __restrict__ adj,
                         float* __restrict__ scores,
                         float* __restrict__ ws) {
    int gtid = blockIdx.x * blockDim.x + threadIdx.x;
    if (gtid < 2 * BB * HH) ws[gtid] = 0.0f;  // zero u0/u1 for k_wsum atomics
    int wave = gtid >> 6;
    int lane = threadIdx.x & 63;
    if (wave >= BB * NN) return;
    const float* wk = w_att + HH;
    size_t base = (size_t)wave * HH;
    float4 k0 = *(const float4*)(K + base + lane * 4);
    float4 k1 = *(const float4*)(K + base + 256 + lane * 4);
    float4 a0 = *(const float4*)(wk + lane * 4);
    float4 a1 = *(const float4*)(wk + 256 + lane * 4);
    float s = dot4(k0, a0) + dot4(k1, a1);
#pragma unroll
    for (int off = 32; off > 0; off >>= 1) s += __shfl_down(s, off, 64);
    if (lane == 0) scores[wave] = adj[wave] ? s : -1e30f;
}

// Kernel 2: per-block softmax stats (redundant per batch, L2-resident reads),
// normalize own 128-row chunk into attn output, and accumulate
//   u0[b,h] += sum_n attn*sm*V[b,n,h] ; u1[b,h] += sum_n attn*(1-sm)*V[b,n,h]
// grid = B*16 blocks x 256 threads; thread covers 4 h, 64 rows.
__global__ void k_wsum(const float* __restrict__ V,
                       const float* __restrict__ scores,
                       float* __restrict__ attn,
                       const int* __restrict__ s_mask,
                       float* __restrict__ u0,
                       float* __restrict__ u1) {
    int b = blockIdx.x >> 4;
    int n0 = (blockIdx.x & 15) * 128;
    int t = threadIdx.x;
    int h4 = (t & 127) * 4;
    int half = t >> 7;  // rows [0,64) or [64,128) of the chunk
    __shared__ float red[4];
    __shared__ float w0s[128], w1s[128], comb[1024];

    // --- stats over the full batch row (2048 scores, ~8 KB from L2) ---
    const float* srow = scores + b * NN;
    float v[8];
    float m = -INFINITY;
#pragma unroll
    for (int i = 0; i < 8; i++) {
        v[i] = srow[t * 8 + i];
        m = fmaxf(m, v[i]);
    }
#pragma unroll
    for (int off = 32; off > 0; off >>= 1) m = fmaxf(m, __shfl_xor(m, off, 64));
    if ((t & 63) == 0) red[t >> 6] = m;
    __syncthreads();
    float m4 = fmaxf(fmaxf(red[0], red[1]), fmaxf(red[2], red[3]));
    float sum = 0.0f;
#pragma unroll
    for (int i = 0; i < 8; i++) sum += expf(v[i] - m4);
#pragma unroll
    for (int off = 32; off > 0; off >>= 1) sum += __shfl_xor(sum, off, 64);
    __syncthreads();
    if ((t & 63) == 0) red[t >> 6] = sum;
    __syncthreads();
    float inv = 1.0f / (red[0] + red[1] + red[2] + red[3]);

    // --- normalize own chunk, write attn output, stage weights in LDS ---
    if (t < 128) {
        float w = expf(srow[n0 + t] - m4) * inv;
        attn[b * NN + n0 + t] = w;  // output 0, normalized
        int sm = s_mask[b * NN + n0 + t];
        w0s[t] = sm ? w : 0.0f;
        w1s[t] = sm ? 0.0f : w;
    }
    __syncthreads();

    // --- weighted V accumulation ---
    float4 a0 = {0, 0, 0, 0}, a1 = {0, 0, 0, 0};
    const float* Vb = V + ((size_t)(b * NN + n0 + half * 64)) * HH + h4;
#pragma unroll 4
    for (int i = 0; i < 64; i++) {
        float4 x = *(const float4*)(Vb + (size_t)i * HH);
        float w0 = w0s[half * 64 + i];
        float w1 = w1s[half * 64 + i];
        a0.x += w0 * x.x; a0.y += w0 * x.y; a0.z += w0 * x.z; a0.w += w0 * x.w;
        a1.x += w1 * x.x; a1.y += w1 * x.y; a1.z += w1 * x.z; a1.w += w1 * x.w;
    }
    // combine the two halves through LDS -> halves the global atomics
    if (half == 1) {
        int i8 = (t - 128) * 8;
        comb[i8 + 0] = a0.x; comb[i8 + 1] = a0.y; comb[i8 + 2] = a0.z; comb[i8 + 3] = a0.w;
        comb[i8 + 4] = a1.x; comb[i8 + 5] = a1.y; comb[i8 + 6] = a1.z; comb[i8 + 7] = a1.w;
    }
    __syncthreads();
    if (half == 0) {
        int i8 = t * 8;
        a0.x += comb[i8 + 0]; a0.y += comb[i8 + 1]; a0.z += comb[i8 + 2]; a0.w += comb[i8 + 3];
        a1.x += comb[i8 + 4]; a1.y += comb[i8 + 5]; a1.z += comb[i8 + 6]; a1.w += comb[i8 + 7];
        float* p0 = u0 + b * HH + h4;
        float* p1 = u1 + b * HH + h4;
        atomicAdd(p0 + 0, a0.x); atomicAdd(p0 + 1, a0.y);
        atomicAdd(p0 + 2, a0.z); atomicAdd(p0 + 3, a0.w);
        atomicAdd(p1 + 0, a1.x); atomicAdd(p1 + 1, a1.y);
        atomicAdd(p1 + 2, a1.z); atomicAdd(p1 + 3, a1.w);
    }
}

// Kernel 3: attn_sum[b,o] = Wr0[o]·u0[b] + Wr1[o]·u1[b] + Wri[o]·Q[b], one wave per (b,o)
__global__ void k_out(const float* __restrict__ Q,
                      const float* __restrict__ Wr0,
                      const float* __restrict__ Wr1,
                      const float* __restrict__ Wri,
                      const float* __restrict__ u0,
                      const float* __restrict__ u1,
                      float* __restrict__ out) {
    int wave = (blockIdx.x * blockDim.x + threadIdx.x) >> 6;
    int lane = threadIdx.x & 63;
    if (wave >= BB * HH) return;
    int b = wave >> 9;
    int o = wave & 511;
    const float* q = Q + b * HH;
    const float* x0 = u0 + b * HH;
    const float* x1 = u1 + b * HH;
    const float* r0 = Wr0 + (size_t)o * HH;
    const float* r1 = Wr1 + (size_t)o * HH;
    const float* ri = Wri + (size_t)o * HH;
    float s = 0.0f;
#pragma unroll
    for (int part = 0; part < 2; part++) {
        int h = part * 256 + lane * 4;
        s += dot4(*(const float4*)(r0 + h), *(const float4*)(x0 + h));
        s += dot4(*(const float4*)(r1 + h), *(const float4*)(x1 + h));
        s += dot4(*(const float4*)(ri + h), *(const float4*)(q + h));
    }
#pragma unroll
    for (int off = 32; off > 0; off >>= 1) s += __shfl_down(s, off, 64);
    if (lane == 0) out[wave] = s;
}

extern "C" void kernel_launch(void* const* d_in, const int* in_sizes, int n_in,
                              void* d_out, int out_size, void* d_ws, size_t ws_size,
                              hipStream_t stream) {
    const float* Q = (const float*)d_in[0];
    const float* K = (const float*)d_in[1];
    const float* V = (const float*)d_in[2];
    const int* adj = (const int*)d_in[3];
    const int* s_mask = (const int*)d_in[4];
    const float* w_att = (const float*)d_in[5];
    // d_in[6] = b_att: unused — softmax invariant to per-row constants.
    const float* Wr0 = (const float*)d_in[7];
    const float* Wr1 = (const float*)d_in[8];
    const float* Wri = (const float*)d_in[9];

    float* out = (float*)d_out;
    float* attn = out;                // B*N floats (output 0)
    float* attn_sum = out + BB * NN;  // B*H floats (output 1)
    float* ws = (float*)d_ws;
    float* u0 = ws;
    float* u1 = ws + BB * HH;
    float* scores = ws + 2 * BB * HH;  // B*N raw scores scratch

    k_scores<<<(BB * NN) / 4, 256, 0, stream>>>(K, w_att, adj, scores, ws);
    k_wsum<<<BB * 16, 256, 0, stream>>>(V, scores, attn, s_mask, u0, u1);
    k_out<<<(BB * HH) / 4, 256, 0, stream>>>(Q, Wr0, Wr1, Wri, u0, u1, attn_sum);
}